// Round 1
// baseline (267.023 us; speedup 1.0000x reference)
//
#include <hip/hip_runtime.h>
#include <hip/hip_bf16.h>

typedef unsigned short u16;
typedef unsigned int   u32;
typedef __attribute__((ext_vector_type(4))) float f32x4;
typedef __attribute__((ext_vector_type(4))) u32   u32x4;
typedef __attribute__((ext_vector_type(8))) short bf16x8;

#define D_CH   256
#define HWPIX  9216      // 96*96
#define NPIX   73728     // 8*96*96
#define LN_EPS 1e-5f
#define ZSTR   264       // bf16 elems per LDS row (256 + 8 pad; 528B stride -> 2-way-free banks)

__device__ __forceinline__ u16 f2bf(float f){
  u32 u = __builtin_bit_cast(u32, f);
  u += 0x7fffu + ((u >> 16) & 1u);          // RTNE
  return (u16)(u >> 16);
}
__device__ __forceinline__ float lo2f(u32 w){ return __builtin_bit_cast(float, w << 16); }
__device__ __forceinline__ float hi2f(u32 w){ return __builtin_bit_cast(float, w & 0xffff0000u); }
__device__ __forceinline__ float bfu2f(u16 h){ return __builtin_bit_cast(float, (u32)h << 16); }
__device__ __forceinline__ float fsigmoid(float v){ return __fdividef(1.f, 1.f + __expf(-v)); }
__device__ __forceinline__ float fsilu(float v){ return __fdividef(v, 1.f + __expf(-v)); }

// ---------------- kernel 1: weight convert + transpose (fp32 [K][N] -> bf16 [N][K]) ----
__global__ __launch_bounds__(256) void wconv(const float* __restrict__ pk,
                                             const float* __restrict__ gk,
                                             u16* __restrict__ wtp,   // [256][1024]
                                             u16* __restrict__ wtg)   // [256][512]
{
  int idx = blockIdx.x * 256 + threadIdx.x;    // grid 1024*256 = 262144 = |pk|
  {
    int k = idx >> 8, n = idx & 255;
    wtp[n * 1024 + k] = f2bf(pk[idx]);
  }
  if (idx < 512 * 256) {
    int k = idx >> 8, n = idx & 255;
    wtg[n * 512 + k] = f2bf(gk[idx]);
  }
}

// ---------------- kernel 2: per-(b,h) partial sums of h_norm over w ----------------
__global__ __launch_bounds__(256) void ln_partial(const float* __restrict__ x,
                                                  const float* __restrict__ g,
                                                  const float* __restrict__ bt,
                                                  float* __restrict__ partial) // [768][256]
{
  const int bh = blockIdx.x;
  const int tid = threadIdx.x;
  const int wv = tid >> 6, lane = tid & 63;
  const float* xrow = x + (size_t)bh * 96 * 256;
  __shared__ float red[4][256];

  f32x4 gv = *(const f32x4*)(g  + lane * 4);
  f32x4 bv = *(const f32x4*)(bt + lane * 4);
  f32x4 acc = {0.f, 0.f, 0.f, 0.f};

  for (int w = wv; w < 96; w += 4) {
    f32x4 v = *(const f32x4*)(xrow + w * 256 + lane * 4);
    float s  = v[0] + v[1] + v[2] + v[3];
    float s2 = v[0]*v[0] + v[1]*v[1] + v[2]*v[2] + v[3]*v[3];
    #pragma unroll
    for (int m = 1; m < 64; m <<= 1) { s += __shfl_xor(s, m); s2 += __shfl_xor(s2, m); }
    float mu  = s * (1.f / 256.f);
    float var = s2 * (1.f / 256.f) - mu * mu;
    float rs  = rsqrtf(var + LN_EPS);
    #pragma unroll
    for (int j = 0; j < 4; ++j) acc[j] += (v[j] - mu) * rs * gv[j] + bv[j];
  }
  *(f32x4*)(&red[wv][lane * 4]) = acc;
  __syncthreads();
  float s = red[0][tid] + red[1][tid] + red[2][tid] + red[3][tid];
  partial[(size_t)bh * 256 + tid] = s;
}

// ---------------- kernel 3: reduce rows -> spatial mean [8][256] -------------------
__global__ __launch_bounds__(256) void ln_mean(const float* __restrict__ partial,
                                               float* __restrict__ mean)
{
  int b = blockIdx.x, c = threadIdx.x;
  float s = 0.f;
  for (int h = 0; h < 96; ++h) s += partial[((size_t)b * 96 + h) * 256 + c];
  mean[b * 256 + c] = s * (1.f / 9216.f);
}

// ---------------- kernel 4: fused main ---------------------------------------------
// 64 pixels/block, 512 threads (8 waves in 2x4 grid), N=256 full.
__global__ __launch_bounds__(512, 1) void fused(
    const float* __restrict__ x,
    const float* __restrict__ lng, const float* __restrict__ lnb,
    const u16*  __restrict__ wtp, const u16* __restrict__ wtg,
    const float* __restrict__ pbias, const float* __restrict__ gbias,
    const float* __restrict__ gamma, const float* __restrict__ meang,
    float* __restrict__ out)
{
  __shared__ u16 zdet[64 * ZSTR];   // h_norm bf16
  __shared__ u16 zctx[64 * ZSTR];   // h_norm - spatial_mean
  __shared__ u16 afg [64 * ZSTR];   // A_comp during GEMM1, g_feat during GEMM2
  __shared__ u16 wtile[256 * 40];   // weight k-chunk [n][32(+8 pad)]

  const int tid  = threadIdx.x;
  const long pix0 = (long)blockIdx.x * 64;
  const int b    = (int)(pix0 / HWPIX);      // tiles never cross batch (9216 % 64 == 0)

  // ---- preproc: LN + context centering, stage z_det/z_ctx as bf16 ----
  {
    const int p = tid >> 3, o = tid & 7;     // 8 lanes per pixel, 32 ch each
    const float* xp = x + (pix0 + p) * 256 + o * 32;
    f32x4 v[8];
    float s = 0.f, s2 = 0.f;
    #pragma unroll
    for (int i = 0; i < 8; ++i) {
      v[i] = *(const f32x4*)(xp + i * 4);
      #pragma unroll
      for (int j = 0; j < 4; ++j) { s += v[i][j]; s2 += v[i][j] * v[i][j]; }
    }
    s += __shfl_xor(s, 1); s2 += __shfl_xor(s2, 1);
    s += __shfl_xor(s, 2); s2 += __shfl_xor(s2, 2);
    s += __shfl_xor(s, 4); s2 += __shfl_xor(s2, 4);
    float mu  = s * (1.f / 256.f);
    float var = s2 * (1.f / 256.f) - mu * mu;
    float rs  = rsqrtf(var + LN_EPS);

    const float* gp = lng + o * 32;
    const float* bp = lnb + o * 32;
    const float* mp = meang + b * 256 + o * 32;
    u16* zd = zdet + p * ZSTR + o * 32;
    u16* zc = zctx + p * ZSTR + o * 32;
    u32 pad_d = 0, pad_c = 0;
    #pragma unroll
    for (int i = 0; i < 8; ++i) {
      f32x4 gg = *(const f32x4*)(gp + i * 4);
      f32x4 bb = *(const f32x4*)(bp + i * 4);
      f32x4 mm = *(const f32x4*)(mp + i * 4);
      float h0 = (v[i][0] - mu) * rs * gg[0] + bb[0];
      float h1 = (v[i][1] - mu) * rs * gg[1] + bb[1];
      float h2 = (v[i][2] - mu) * rs * gg[2] + bb[2];
      float h3 = (v[i][3] - mu) * rs * gg[3] + bb[3];
      u32 d0 = (u32)f2bf(h0) | ((u32)f2bf(h1) << 16);
      u32 d1 = (u32)f2bf(h2) | ((u32)f2bf(h3) << 16);
      u32 c0 = (u32)f2bf(h0 - mm[0]) | ((u32)f2bf(h1 - mm[1]) << 16);
      u32 c1 = (u32)f2bf(h2 - mm[2]) | ((u32)f2bf(h3 - mm[3]) << 16);
      *(u32*)(zd + i * 4)     = d0;
      *(u32*)(zd + i * 4 + 2) = d1;
      *(u32*)(zc + i * 4)     = c0;
      *(u32*)(zc + i * 4 + 2) = c1;
      if (i == 0) { pad_d = d0; pad_c = c0; }
    }
    if (o == 0) {      // wrap pad: elements [256,257] = [0,1] (max roll shift = 2)
      *(u32*)(zdet + p * ZSTR + 256) = pad_d;
      *(u32*)(zctx + p * ZSTR + 256) = pad_c;
    }
  }

  // ---- GEMM setup ----
  const int wave = tid >> 6, lane = tid & 63;
  const int wr = wave & 1, wc = wave >> 1;        // 2x4 wave grid
  const int fr = lane & 15, kq = lane >> 4;       // fragment row/col, k-quarter
  const int sn = tid >> 1, sh_ = tid & 1;         // weight staging: n-row, 16-elem half

  f32x4 acc[2][4];
  f32x4 gf [2][4];
  #pragma unroll
  for (int i = 0; i < 2; ++i)
    #pragma unroll
    for (int j = 0; j < 4; ++j) acc[i][j] = {0.f, 0.f, 0.f, 0.f};

  u32x4 wreg0, wreg1;
  auto load_w1 = [&](int comp, int kk) {
    const u16* src = wtp + sn * 1024 + comp * 256 + kk * 32 + sh_ * 16;
    wreg0 = *(const u32x4*)src;
    wreg1 = *(const u32x4*)(src + 8);
  };
  auto load_w2 = [&](int kk) {
    const u16* src = wtg + sn * 512 + kk * 32 + sh_ * 16;
    wreg0 = *(const u32x4*)src;
    wreg1 = *(const u32x4*)(src + 8);
  };
  auto store_w = [&]() {
    u16* dst = wtile + sn * 40 + sh_ * 16;
    *(u32x4*)dst       = wreg0;
    *(u32x4*)(dst + 8) = wreg1;
  };
  auto mfma_step = [&](const u16* abase, int kelem) {
    bf16x8 a0 = *(const bf16x8*)(abase + (wr * 32 +      fr) * ZSTR + kelem + kq * 8);
    bf16x8 a1 = *(const bf16x8*)(abase + (wr * 32 + 16 + fr) * ZSTR + kelem + kq * 8);
    #pragma unroll
    for (int nt = 0; nt < 4; ++nt) {
      bf16x8 bb = *(const bf16x8*)(wtile + (wc * 64 + nt * 16 + fr) * 40 + kq * 8);
      acc[0][nt] = __builtin_amdgcn_mfma_f32_16x16x32_bf16(a0, bb, acc[0][nt], 0, 0, 0);
      acc[1][nt] = __builtin_amdgcn_mfma_f32_16x16x32_bf16(a1, bb, acc[1][nt], 0, 0, 0);
    }
  };

  // ---- GEMM1: g_feat_pre = feats @ Wp, K = 4 comps x 256 ----
  for (int comp = 0; comp < 4; ++comp) {
    load_w1(comp, 0);
    __syncthreads();                    // afg free (prev comp read) / preproc visible
    {   // build A_comp into afg: feats for this component
      const int p = tid >> 3, o = tid & 7;
      const int s = 1 + (comp >> 1);
      const bool isdot = (comp & 1) == 0;
      const u16* zd = zdet + p * ZSTR + o * 32;
      const u16* zc = zctx + p * ZSTR + o * 32;
      u16* ao = afg + p * ZSTR + o * 32;
      u32x4 da = *(const u32x4*)zd;
      u32x4 ca = *(const u32x4*)zc;
      #pragma unroll
      for (int gi = 0; gi < 4; ++gi) {
        u32x4 db = *(const u32x4*)(zd + gi * 8 + 8);
        u32x4 cb = *(const u32x4*)(zc + gi * 8 + 8);
        u32x4 dsh, csh;
        if (s == 1) {
          dsh[0]=(da[0]>>16)|(da[1]<<16); dsh[1]=(da[1]>>16)|(da[2]<<16);
          dsh[2]=(da[2]>>16)|(da[3]<<16); dsh[3]=(da[3]>>16)|(db[0]<<16);
          csh[0]=(ca[0]>>16)|(ca[1]<<16); csh[1]=(ca[1]>>16)|(ca[2]<<16);
          csh[2]=(ca[2]>>16)|(ca[3]<<16); csh[3]=(ca[3]>>16)|(cb[0]<<16);
        } else {
          dsh[0]=da[1]; dsh[1]=da[2]; dsh[2]=da[3]; dsh[3]=db[0];
          csh[0]=ca[1]; csh[1]=ca[2]; csh[2]=ca[3]; csh[3]=cb[0];
        }
        u32x4 ow;
        #pragma unroll
        for (int wd = 0; wd < 4; ++wd) {
          float zd0 = lo2f(da[wd]),  zd1 = hi2f(da[wd]);
          float zs0 = lo2f(csh[wd]), zs1 = hi2f(csh[wd]);
          float r0, r1;
          if (isdot) {
            float t0 = zd0 * zs0, t1 = zd1 * zs1;
            r0 = fsilu(t0); r1 = fsilu(t1);
          } else {
            float zc0 = lo2f(ca[wd]),  zc1 = hi2f(ca[wd]);
            float ds0 = lo2f(dsh[wd]), ds1 = hi2f(dsh[wd]);
            r0 = zd0 * zs0 - zc0 * ds0;
            r1 = zd1 * zs1 - zc1 * ds1;
          }
          ow[wd] = (u32)f2bf(r0) | ((u32)f2bf(r1) << 16);
        }
        *(u32x4*)(ao + gi * 8) = ow;
        da = db; ca = cb;
      }
    }
    for (int kk = 0; kk < 8; ++kk) {
      __syncthreads();                  // A ready (kk=0) / wtile free
      store_w();
      __syncthreads();                  // wtile ready
      if (kk < 7) load_w1(comp, kk + 1);
      mfma_step(afg, kk * 32);
    }
  }

  // ---- epilogue 1: g_feat = acc + pbias -> regs + LDS(bf16), reset acc ----
  load_w2(0);                           // prefetch gate weights k-chunk 0
  __syncthreads();                      // GEMM1 reads of afg/wtile done
  #pragma unroll
  for (int mt = 0; mt < 2; ++mt) {
    #pragma unroll
    for (int nt = 0; nt < 4; ++nt) {
      int col = wc * 64 + nt * 16 + fr;
      float pb = pbias[col];
      #pragma unroll
      for (int rr = 0; rr < 4; ++rr) {
        int row = wr * 32 + mt * 16 + kq * 4 + rr;
        float gv = acc[mt][nt][rr] + pb;
        gf[mt][nt][rr] = gv;
        afg[row * ZSTR + col] = f2bf(gv);
      }
      acc[mt][nt] = {0.f, 0.f, 0.f, 0.f};
    }
  }

  // ---- GEMM2: alpha_pre = [h_norm | g_feat] @ Wg, K = 512 ----
  for (int kk = 0; kk < 16; ++kk) {
    __syncthreads();                    // g_feat visible (kk=0) / wtile free
    store_w();
    __syncthreads();                    // wtile ready
    if (kk < 15) load_w2(kk + 1);
    const u16* ab = (kk < 8) ? zdet : afg;
    mfma_step(ab, (kk & 7) * 32);
  }

  // ---- epilogue 2: alpha, silu, LayerScale, residual ----
  #pragma unroll
  for (int mt = 0; mt < 2; ++mt) {
    #pragma unroll
    for (int nt = 0; nt < 4; ++nt) {
      int col = wc * 64 + nt * 16 + fr;
      float gb = gbias[col];
      float gm = gamma[col];
      #pragma unroll
      for (int rr = 0; rr < 4; ++rr) {
        int row = wr * 32 + mt * 16 + kq * 4 + rr;
        float al = fsigmoid(acc[mt][nt][rr] + gb);
        float h  = bfu2f(zdet[row * ZSTR + col]);
        float hm = (fsilu(h) + al * gf[mt][nt][rr]) * gm;
        long gi = (pix0 + row) * 256 + col;
        out[gi] = x[gi] + hm;
      }
    }
  }
}

extern "C" void kernel_launch(void* const* d_in, const int* in_sizes, int n_in,
                              void* d_out, int out_size, void* d_ws, size_t ws_size,
                              hipStream_t stream) {
  const float* x     = (const float*)d_in[0];
  const float* lng   = (const float*)d_in[1];
  const float* lnb   = (const float*)d_in[2];
  const float* pk    = (const float*)d_in[3];
  const float* pbias = (const float*)d_in[4];
  const float* gk    = (const float*)d_in[5];
  const float* gbias = (const float*)d_in[6];
  const float* gamma = (const float*)d_in[7];
  float* out = (float*)d_out;

  char* ws = (char*)d_ws;
  u16*   wtp     = (u16*)ws;                       // 524288 B
  u16*   wtg     = (u16*)(ws + 524288);            // 262144 B
  float* partial = (float*)(ws + 786432);          // 786432 B
  float* meang   = (float*)(ws + 1572864);         // 8192 B  (total ~1.55 MB)

  wconv<<<1024, 256, 0, stream>>>(pk, gk, wtp, wtg);
  ln_partial<<<768, 256, 0, stream>>>(x, lng, lnb, partial);
  ln_mean<<<8, 256, 0, stream>>>(partial, meang);
  fused<<<NPIX / 64, 512, 0, stream>>>(x, lng, lnb, wtp, wtg,
                                       pbias, gbias, gamma, meang, out);
}